// Round 1
// baseline (386.685 us; speedup 1.0000x reference)
//
#include <hip/hip_runtime.h>
#include <hip/hip_bf16.h>

#define B_ 2
#define S_ 8192
#define DIM_ 1024
#define NH_ 16
#define NKV_ 4
#define HD_ 64
#define NC_ 64

typedef __bf16 bf16x8 __attribute__((ext_vector_type(8)));
typedef float f32x4 __attribute__((ext_vector_type(4)));
using bf16 = __hip_bfloat16;

// ---------------- fp32 -> bf16 convert (4 elems/thread) ----------------
__global__ __launch_bounds__(256) void f2b4_kernel(const float* __restrict__ in, bf16* __restrict__ out) {
    size_t i = ((size_t)blockIdx.x * 256 + threadIdx.x) * 4;
    const float4 f = *(const float4*)(in + i);
    bf16 t[4];
    t[0] = __float2bfloat16(f.x); t[1] = __float2bfloat16(f.y);
    t[2] = __float2bfloat16(f.z); t[3] = __float2bfloat16(f.w);
    *(uint2*)(out + i) = *(const uint2*)t;
}

// ---------------- RoPE tables (f64 to match numpy ref) ----------------
__global__ __launch_bounds__(256) void rope_tab_kernel(float* __restrict__ cosd, float* __restrict__ sind) {
    int idx = blockIdx.x * 256 + threadIdx.x;  // S_*32
    int s = idx >> 5, i = idx & 31;
    double inv = exp(((double)(-2 * i) / 64.0) * log(10000.0));
    double ang = (double)s * inv;
    cosd[idx] = (float)cos(ang);
    sind[idx] = (float)sin(ang);
}

// ---------------- RoPE apply, in place (pair i, i+32 per thread) ----------------
__global__ __launch_bounds__(256) void rope_apply_kernel(bf16* __restrict__ buf, const float* __restrict__ cosd,
                                                         const float* __restrict__ sind, int nh) {
    size_t idx = (size_t)blockIdx.x * 256 + threadIdx.x;  // B_*S_*nh*32
    int i = (int)(idx & 31);
    int hh = (int)((idx >> 5) % nh);
    size_t r = idx / ((size_t)nh * 32);
    int s = (int)(r & (S_ - 1));
    bf16* p = buf + r * ((size_t)nh * 64) + hh * 64 + i;
    float x1 = __bfloat162float(p[0]);
    float x2 = __bfloat162float(p[32]);
    float cs = cosd[(s << 5) + i];
    float sn = sind[(s << 5) + i];
    p[0]  = __float2bfloat16(x1 * cs - x2 * sn);
    p[32] = __float2bfloat16(x2 * cs + x1 * sn);
}

// ---------------- C[M][N] = A[M][K] * B[N][K]^T, bf16 in, OT out ----------------
template <typename OT>
__global__ __launch_bounds__(256) void gemm_bt_kernel(const bf16* __restrict__ A, const bf16* __restrict__ Bm,
                                                      OT* __restrict__ C, int M, int N, int K) {
    __shared__ bf16 As[128][72];
    __shared__ bf16 Bs[128][72];
    const int tid = threadIdx.x;
    const int bm = blockIdx.y * 128, bn = blockIdx.x * 128;
    const int wave = tid >> 6, lane = tid & 63;
    const int wm = (wave >> 1) * 64, wn = (wave & 1) * 64;
    const int lr = lane & 15, quad = lane >> 4;
    f32x4 acc[4][4] = {};
    for (int k0 = 0; k0 < K; k0 += 64) {
#pragma unroll
        for (int p = 0; p < 4; ++p) {
            int flat = p * 256 + tid;
            int r = flat >> 3, c8 = (flat & 7) * 8;
            *(uint4*)(&As[r][c8]) = *(const uint4*)(A + (size_t)(bm + r) * K + k0 + c8);
            *(uint4*)(&Bs[r][c8]) = *(const uint4*)(Bm + (size_t)(bn + r) * K + k0 + c8);
        }
        __syncthreads();
#pragma unroll
        for (int kk = 0; kk < 64; kk += 32) {
            bf16x8 af[4], bfr[4];
#pragma unroll
            for (int i = 0; i < 4; ++i) af[i] = *(const bf16x8*)(&As[wm + i * 16 + lr][kk + quad * 8]);
#pragma unroll
            for (int i = 0; i < 4; ++i) bfr[i] = *(const bf16x8*)(&Bs[wn + i * 16 + lr][kk + quad * 8]);
#pragma unroll
            for (int mi = 0; mi < 4; ++mi)
#pragma unroll
                for (int ni = 0; ni < 4; ++ni)
                    acc[mi][ni] = __builtin_amdgcn_mfma_f32_16x16x32_bf16(af[mi], bfr[ni], acc[mi][ni], 0, 0, 0);
        }
        __syncthreads();
    }
#pragma unroll
    for (int mi = 0; mi < 4; ++mi)
#pragma unroll
        for (int ni = 0; ni < 4; ++ni)
#pragma unroll
            for (int r = 0; r < 4; ++r) {
                int row = bm + wm + mi * 16 + quad * 4 + r;
                int col = bn + wn + ni * 16 + lr;
                float v = acc[mi][ni][r];
                if constexpr (__is_same(OT, float)) C[(size_t)row * N + col] = v;
                else C[(size_t)row * N + col] = __float2bfloat16(v);
            }
}

// ---------------- per-chunk KV contribution: CT[e][d] = sum_t v[t][e]*k[t][d]*kdec[t] ----------------
__global__ __launch_bounds__(256) void chunk_kv_kernel(const bf16* __restrict__ kbuf, const bf16* __restrict__ vbuf,
                                                       float* __restrict__ Cout) {
    const int j = blockIdx.x, h = blockIdx.y, b = blockIdx.z;
    const int g = h >> 2;
    const float slope = exp2f(-0.5f * (float)(h + 1));
    __shared__ bf16 kdT[64][136];
    __shared__ bf16 vT[64][136];
    const int tid = threadIdx.x;
#pragma unroll
    for (int p = 0; p < 4; ++p) {
        int flat = p * 256 + tid;
        int t = flat >> 3, d0 = (flat & 7) * 8;
        const size_t row = (size_t)(b * S_ + j * 128 + t);
        uint4 kw = *(const uint4*)(kbuf + row * (NKV_ * 64) + g * 64 + d0);
        uint4 vw = *(const uint4*)(vbuf + row * (NKV_ * 64) + g * 64 + d0);
        float kdec = __expf(-slope * (float)(127 - t));
        const bf16* kp = (const bf16*)&kw;
        const bf16* vp = (const bf16*)&vw;
#pragma unroll
        for (int i = 0; i < 8; ++i) {
            kdT[d0 + i][t] = __float2bfloat16(__bfloat162float(kp[i]) * kdec);
            vT[d0 + i][t] = vp[i];
        }
    }
    __syncthreads();
    const int wave = tid >> 6, lane = tid & 63, lr = lane & 15, quad = lane >> 4;
    const int e0 = wave * 16;
    f32x4 acc[4] = {};
#pragma unroll
    for (int ks = 0; ks < 128; ks += 32) {
        bf16x8 a = *(const bf16x8*)(&vT[e0 + lr][ks + quad * 8]);
#pragma unroll
        for (int ni = 0; ni < 4; ++ni) {
            bf16x8 bb = *(const bf16x8*)(&kdT[ni * 16 + lr][ks + quad * 8]);
            acc[ni] = __builtin_amdgcn_mfma_f32_16x16x32_bf16(a, bb, acc[ni], 0, 0, 0);
        }
    }
    float* out = Cout + ((size_t)((b * NH_ + h) * NC_ + j)) * 4096;
#pragma unroll
    for (int ni = 0; ni < 4; ++ni)
#pragma unroll
        for (int r = 0; r < 4; ++r)
            out[(e0 + quad * 4 + r) * 64 + ni * 16 + lr] = acc[ni][r];
}

// ---------------- exclusive decay scan over chunks: state[c] = sum_{j<c} bdec^{c-1-j} C[j] ----------------
__global__ __launch_bounds__(512) void scan_kv_kernel(const float* __restrict__ Cin, bf16* __restrict__ st) {
    const int bh = blockIdx.x;  // B_*NH_
    const int h = bh & (NH_ - 1);
    const float slope = exp2f(-0.5f * (float)(h + 1));
    const float bdec = __expf(-slope * 128.0f);
    const int tid = threadIdx.x;
    float carry[8];
#pragma unroll
    for (int i = 0; i < 8; ++i) carry[i] = 0.f;
    const float* Cb = Cin + (size_t)bh * NC_ * 4096;
    bf16* sb = st + (size_t)bh * NC_ * 4096;
    for (int c = 0; c < NC_; ++c) {
#pragma unroll
        for (int i = 0; i < 8; ++i) {
            int f = i * 512 + tid;
            sb[(size_t)c * 4096 + f] = __float2bfloat16(carry[i]);
            carry[i] = bdec * carry[i] + Cb[(size_t)c * 4096 + f];
        }
    }
}

// ---------------- per-chunk output: O = (mask ∘ qk^T) v + (q*qdec) kv ----------------
__global__ __launch_bounds__(256) void attn_chunk_kernel(const bf16* __restrict__ q, const bf16* __restrict__ k,
                                                         const bf16* __restrict__ v, const bf16* __restrict__ kvst,
                                                         bf16* __restrict__ outb) {
    const int c = blockIdx.x, h = blockIdx.y, b = blockIdx.z;
    const int g = h >> 2;
    const float slope = exp2f(-0.5f * (float)(h + 1));
    __shared__ bf16 qs[128][72];
    __shared__ bf16 ub[128 * 72];   // phase1: k[t][d] stride 72; phase2: vT[e][t] stride 136
    __shared__ bf16 Ps[128][136];
    const int tid = threadIdx.x;
    const int wave = tid >> 6, lane = tid & 63, lr = lane & 15, quad = lane >> 4;
#pragma unroll
    for (int p = 0; p < 4; ++p) {
        int flat = p * 256 + tid;
        int t = flat >> 3, d0 = (flat & 7) * 8;
        size_t row = (size_t)(b * S_ + c * 128 + t);
        *(uint4*)(&qs[t][d0]) = *(const uint4*)(q + row * (NH_ * 64) + h * 64 + d0);
        *(uint4*)(&ub[t * 72 + d0]) = *(const uint4*)(k + row * (NKV_ * 64) + g * 64 + d0);
    }
    __syncthreads();
    const int m0 = wave * 32;
    f32x4 sacc[2][8] = {};
#pragma unroll
    for (int kk = 0; kk < 64; kk += 32) {
        bf16x8 af0 = *(const bf16x8*)(&qs[m0 + lr][kk + quad * 8]);
        bf16x8 af1 = *(const bf16x8*)(&qs[m0 + 16 + lr][kk + quad * 8]);
#pragma unroll
        for (int ni = 0; ni < 8; ++ni) {
            bf16x8 bfr = *(const bf16x8*)(&ub[(ni * 16 + lr) * 72 + kk + quad * 8]);
            sacc[0][ni] = __builtin_amdgcn_mfma_f32_16x16x32_bf16(af0, bfr, sacc[0][ni], 0, 0, 0);
            sacc[1][ni] = __builtin_amdgcn_mfma_f32_16x16x32_bf16(af1, bfr, sacc[1][ni], 0, 0, 0);
        }
    }
    __syncthreads();  // all waves done reading ub (k) before it is overwritten by vT
    // mask + write P (each wave writes only its own 32-row strip)
#pragma unroll
    for (int mi = 0; mi < 2; ++mi)
#pragma unroll
        for (int ni = 0; ni < 8; ++ni)
#pragma unroll
            for (int r = 0; r < 4; ++r) {
                int t = m0 + mi * 16 + quad * 4 + r;
                int tp = ni * 16 + lr;
                int del = t - tp;
                float val = (del >= 0) ? sacc[mi][ni][r] * __expf(-slope * (float)del) : 0.f;
                Ps[t][tp] = __float2bfloat16(val);
            }
    // stage v transposed into ub
#pragma unroll
    for (int p = 0; p < 4; ++p) {
        int flat = p * 256 + tid;
        int t = flat >> 3, d0 = (flat & 7) * 8;
        size_t row = (size_t)(b * S_ + c * 128 + t);
        uint4 vw = *(const uint4*)(v + row * (NKV_ * 64) + g * 64 + d0);
        const bf16* vp = (const bf16*)&vw;
#pragma unroll
        for (int i = 0; i < 8; ++i) ub[(d0 + i) * 136 + t] = vp[i];
    }
    __syncthreads();
    f32x4 oacc[2][4] = {};
#pragma unroll
    for (int ks2 = 0; ks2 < 128; ks2 += 32) {
        bf16x8 af0 = *(const bf16x8*)(&Ps[m0 + lr][ks2 + quad * 8]);
        bf16x8 af1 = *(const bf16x8*)(&Ps[m0 + 16 + lr][ks2 + quad * 8]);
#pragma unroll
        for (int ni = 0; ni < 4; ++ni) {
            bf16x8 bfv = *(const bf16x8*)(&ub[(ni * 16 + lr) * 136 + ks2 + quad * 8]);
            oacc[0][ni] = __builtin_amdgcn_mfma_f32_16x16x32_bf16(af0, bfv, oacc[0][ni], 0, 0, 0);
            oacc[1][ni] = __builtin_amdgcn_mfma_f32_16x16x32_bf16(af1, bfv, oacc[1][ni], 0, 0, 0);
        }
    }
    const bf16* kvb = kvst + ((size_t)((b * NH_ + h) * NC_ + c)) * 4096;
#pragma unroll
    for (int kk = 0; kk < 64; kk += 32) {
        bf16x8 af[2];
#pragma unroll
        for (int mi = 0; mi < 2; ++mi) {
            bf16x8 a0 = *(const bf16x8*)(&qs[m0 + mi * 16 + lr][kk + quad * 8]);
            float qd = __expf(-slope * (float)(m0 + mi * 16 + lr + 1));
#pragma unroll
            for (int i = 0; i < 8; ++i) a0[i] = (__bf16)((float)a0[i] * qd);
            af[mi] = a0;
        }
#pragma unroll
        for (int ni = 0; ni < 4; ++ni) {
            bf16x8 bk = *(const bf16x8*)(kvb + (ni * 16 + lr) * 64 + kk + quad * 8);
            oacc[0][ni] = __builtin_amdgcn_mfma_f32_16x16x32_bf16(af[0], bk, oacc[0][ni], 0, 0, 0);
            oacc[1][ni] = __builtin_amdgcn_mfma_f32_16x16x32_bf16(af[1], bk, oacc[1][ni], 0, 0, 0);
        }
    }
#pragma unroll
    for (int mi = 0; mi < 2; ++mi)
#pragma unroll
        for (int ni = 0; ni < 4; ++ni)
#pragma unroll
            for (int r = 0; r < 4; ++r) {
                int t = m0 + mi * 16 + quad * 4 + r;
                int e = ni * 16 + lr;
                size_t row = (size_t)(b * S_ + c * 128 + t);
                outb[row * (NH_ * 64) + h * 64 + e] = __float2bfloat16(oacc[mi][ni][r]);
            }
}

extern "C" void kernel_launch(void* const* d_in, const int* in_sizes, int n_in,
                              void* d_out, int out_size, void* d_ws, size_t ws_size,
                              hipStream_t stream) {
    (void)in_sizes; (void)n_in; (void)out_size; (void)ws_size;
    const float* x  = (const float*)d_in[0];
    const float* Wq = (const float*)d_in[1];
    const float* Wk = (const float*)d_in[2];
    const float* Wv = (const float*)d_in[3];
    const float* Wo = (const float*)d_in[4];
    float* out = (float*)d_out;
    char* ws = (char*)d_ws;
    bf16*  xb   = (bf16*)(ws);                    // 33,554,432  (reused as attn_out)
    bf16*  qb   = (bf16*)(ws + 33554432);         // 33,554,432
    bf16*  kb   = (bf16*)(ws + 67108864);         //  8,388,608
    bf16*  vb   = (bf16*)(ws + 75497472);         //  8,388,608
    bf16*  wqb  = (bf16*)(ws + 83886080);         //  2,097,152
    bf16*  wkb  = (bf16*)(ws + 85983232);         //    524,288
    bf16*  wvb  = (bf16*)(ws + 86507520);         //    524,288
    bf16*  wob  = (bf16*)(ws + 87031808);         //  2,097,152
    float* cosd = (float*)(ws + 89128960);        //  1,048,576
    float* sind = (float*)(ws + 90177536);        //  1,048,576
    float* Cbuf = (float*)(ws + 91226112);        // 33,554,432
    bf16*  kvst = (bf16*)(ws + 124780544);        // 16,777,216  -> total 141,557,760 B
    bf16*  attn = xb;

    f2b4_kernel<<<16384, 256, 0, stream>>>(x, xb);
    f2b4_kernel<<<1024, 256, 0, stream>>>(Wq, wqb);
    f2b4_kernel<<<256, 256, 0, stream>>>(Wk, wkb);
    f2b4_kernel<<<256, 256, 0, stream>>>(Wv, wvb);
    f2b4_kernel<<<1024, 256, 0, stream>>>(Wo, wob);
    rope_tab_kernel<<<(S_ * 32) / 256, 256, 0, stream>>>(cosd, sind);

    gemm_bt_kernel<bf16><<<dim3(8, 128), 256, 0, stream>>>(xb, wqb, qb, 16384, 1024, 1024);
    gemm_bt_kernel<bf16><<<dim3(2, 128), 256, 0, stream>>>(xb, wkb, kb, 16384, 256, 1024);
    gemm_bt_kernel<bf16><<<dim3(2, 128), 256, 0, stream>>>(xb, wvb, vb, 16384, 256, 1024);

    rope_apply_kernel<<<(B_ * S_ * NH_ * 32) / 256, 256, 0, stream>>>(qb, cosd, sind, NH_);
    rope_apply_kernel<<<(B_ * S_ * NKV_ * 32) / 256, 256, 0, stream>>>(kb, cosd, sind, NKV_);

    chunk_kv_kernel<<<dim3(NC_, NH_, B_), 256, 0, stream>>>(kb, vb, Cbuf);
    scan_kv_kernel<<<B_ * NH_, 512, 0, stream>>>(Cbuf, kvst);
    attn_chunk_kernel<<<dim3(NC_, NH_, B_), 256, 0, stream>>>(qb, kb, vb, kvst, attn);

    gemm_bt_kernel<float><<<dim3(8, 128), 256, 0, stream>>>(attn, wob, out, 16384, 1024, 1024);
}

// Round 2
// 336.449 us; speedup vs baseline: 1.1493x; 1.1493x over previous
//
#include <hip/hip_runtime.h>
#include <hip/hip_bf16.h>

#define B_ 2
#define S_ 8192
#define DIM_ 1024
#define NH_ 16
#define NKV_ 4
#define HD_ 64
#define NC_ 64

typedef __bf16 bf16x8 __attribute__((ext_vector_type(8)));
typedef float f32x4 __attribute__((ext_vector_type(4)));
using bf16 = __hip_bfloat16;

// async global->LDS, 16B per lane; LDS dst = base + lane*16 (wave-uniform base)
#define ASYNC16(gp, lp) __builtin_amdgcn_global_load_lds( \
    (__attribute__((address_space(1))) void*)(void*)(gp), \
    (__attribute__((address_space(3))) void*)(void*)(lp), 16, 0, 0)

// ---------------- fp32 -> bf16 convert (4 elems/thread) ----------------
__global__ __launch_bounds__(256) void f2b4_kernel(const float* __restrict__ in, bf16* __restrict__ out) {
    size_t i = ((size_t)blockIdx.x * 256 + threadIdx.x) * 4;
    const float4 f = *(const float4*)(in + i);
    bf16 t[4];
    t[0] = __float2bfloat16(f.x); t[1] = __float2bfloat16(f.y);
    t[2] = __float2bfloat16(f.z); t[3] = __float2bfloat16(f.w);
    *(uint2*)(out + i) = *(const uint2*)t;
}

// ---------------- RoPE tables: f64 range-reduction + hw sin/cos ----------------
__global__ __launch_bounds__(256) void rope_tab_kernel(float* __restrict__ cosd, float* __restrict__ sind) {
    int idx = blockIdx.x * 256 + threadIdx.x;  // S_*32
    int s = idx >> 5, i = idx & 31;
    double inv = exp((double)i * (-9.210340371976184 / 32.0));  // 10000^(-i/32)
    double rev = ((double)s * inv) * 0.15915494309189535;       // angle / 2pi
    double frac = rev - floor(rev);
    float a = (float)frac * 6.2831853071795865f;
    cosd[idx] = __cosf(a);
    sind[idx] = __sinf(a);
}

// ---------------- C[M][N] = A[M][K]*B[N][K]^T, bf16 in, OT out, optional fused RoPE ----
// grid (M/128, N/128): x = M-tile so blocks sharing an A-tile have equal id%8 (same XCD).
template <typename OT, bool ROPE>
__global__ __launch_bounds__(256) void gemm_bt_kernel(const bf16* __restrict__ A, const bf16* __restrict__ Bm,
                                                      OT* __restrict__ C, int M, int N, int K,
                                                      const float* __restrict__ cosd,
                                                      const float* __restrict__ sind) {
    __shared__ bf16 As[128 * 64];
    __shared__ bf16 Bs[128 * 64];
    const int tid = threadIdx.x;
    const int bm = blockIdx.x * 128, bn = blockIdx.y * 128;
    const int wave = tid >> 6, lane = tid & 63;
    const int wm = (wave >> 1) * 64, wn = (wave & 1) * 64;
    const int lr = lane & 15, quad = lane >> 4;
    // staging: wave stages rows [wave*32, wave*32+32) of both tiles, 4 instrs of 8 rows
    const int srow = wave * 32;
    const int lrow = lane >> 3;                        // 0..7
    const int lchunk = ((lane & 7) ^ lrow) * 8;        // XOR-swizzled source chunk (elems)
    const bf16* Ag = A + (size_t)(bm + srow + lrow) * K + lchunk;
    const bf16* Bg = Bm + (size_t)(bn + srow + lrow) * K + lchunk;
    f32x4 acc[4][4] = {};
    for (int k0 = 0; k0 < K; k0 += 64) {
#pragma unroll
        for (int p = 0; p < 4; ++p) {
            ASYNC16(Ag + (size_t)(p * 8) * K + k0, &As[(srow + p * 8) * 64]);
            ASYNC16(Bg + (size_t)(p * 8) * K + k0, &Bs[(srow + p * 8) * 64]);
        }
        __syncthreads();
#pragma unroll
        for (int kk = 0; kk < 64; kk += 32) {
            const int sw = (((kk >> 3) + quad) ^ (lr & 7)) << 3;  // de-swizzled chunk offset
            bf16x8 af[4], bfr[4];
#pragma unroll
            for (int i = 0; i < 4; ++i) af[i] = *(const bf16x8*)(&As[(wm + i * 16 + lr) * 64 + sw]);
#pragma unroll
            for (int i = 0; i < 4; ++i) bfr[i] = *(const bf16x8*)(&Bs[(wn + i * 16 + lr) * 64 + sw]);
#pragma unroll
            for (int mi = 0; mi < 4; ++mi)
#pragma unroll
                for (int ni = 0; ni < 4; ++ni)
                    acc[mi][ni] = __builtin_amdgcn_mfma_f32_16x16x32_bf16(af[mi], bfr[ni], acc[mi][ni], 0, 0, 0);
        }
        __syncthreads();
    }
    if constexpr (ROPE) {
        // wave's 64 columns = exactly one head (bn+wn aligned to 64); pair (i, i+32) =
        // (acc[mi][ni], acc[mi][ni+2]) in the same lane, i = ni*16+lr for ni in {0,1}.
#pragma unroll
        for (int mi = 0; mi < 4; ++mi)
#pragma unroll
            for (int r = 0; r < 4; ++r) {
                int row = bm + wm + mi * 16 + quad * 4 + r;
                int s = row & (S_ - 1);
#pragma unroll
                for (int ni = 0; ni < 2; ++ni) {
                    int i = ni * 16 + lr;
                    float cs = cosd[(s << 5) + i];
                    float sn = sind[(s << 5) + i];
                    float x1 = acc[mi][ni][r], x2 = acc[mi][ni + 2][r];
                    acc[mi][ni][r] = x1 * cs - x2 * sn;
                    acc[mi][ni + 2][r] = x2 * cs + x1 * sn;
                }
            }
    }
#pragma unroll
    for (int mi = 0; mi < 4; ++mi)
#pragma unroll
        for (int ni = 0; ni < 4; ++ni)
#pragma unroll
            for (int r = 0; r < 4; ++r) {
                int row = bm + wm + mi * 16 + quad * 4 + r;
                int col = bn + wn + ni * 16 + lr;
                float v = acc[mi][ni][r];
                if constexpr (__is_same(OT, float)) C[(size_t)row * N + col] = v;
                else C[(size_t)row * N + col] = __float2bfloat16(v);
            }
}

// ---------------- per-chunk KV contribution: CT[e][d] = sum_t v[t][e]*k[t][d]*kdec[t] ----------------
__global__ __launch_bounds__(256) void chunk_kv_kernel(const bf16* __restrict__ kbuf, const bf16* __restrict__ vbuf,
                                                       float* __restrict__ Cout) {
    const int j = blockIdx.x, h = blockIdx.y, b = blockIdx.z;
    const int g = h >> 2;
    const float slope = exp2f(-0.5f * (float)(h + 1));
    __shared__ bf16 kdT[64][136];
    __shared__ bf16 vT[64][136];
    const int tid = threadIdx.x;
#pragma unroll
    for (int p = 0; p < 4; ++p) {
        int flat = p * 256 + tid;
        int t = flat >> 3, d0 = (flat & 7) * 8;
        const size_t row = (size_t)(b * S_ + j * 128 + t);
        uint4 kw = *(const uint4*)(kbuf + row * (NKV_ * 64) + g * 64 + d0);
        uint4 vw = *(const uint4*)(vbuf + row * (NKV_ * 64) + g * 64 + d0);
        float kdec = __expf(-slope * (float)(127 - t));
        const bf16* kp = (const bf16*)&kw;
        const bf16* vp = (const bf16*)&vw;
#pragma unroll
        for (int i = 0; i < 8; ++i) {
            kdT[d0 + i][t] = __float2bfloat16(__bfloat162float(kp[i]) * kdec);
            vT[d0 + i][t] = vp[i];
        }
    }
    __syncthreads();
    const int wave = tid >> 6, lane = tid & 63, lr = lane & 15, quad = lane >> 4;
    const int e0 = wave * 16;
    f32x4 acc[4] = {};
#pragma unroll
    for (int ks = 0; ks < 128; ks += 32) {
        bf16x8 a = *(const bf16x8*)(&vT[e0 + lr][ks + quad * 8]);
#pragma unroll
        for (int ni = 0; ni < 4; ++ni) {
            bf16x8 bb = *(const bf16x8*)(&kdT[ni * 16 + lr][ks + quad * 8]);
            acc[ni] = __builtin_amdgcn_mfma_f32_16x16x32_bf16(a, bb, acc[ni], 0, 0, 0);
        }
    }
    float* out = Cout + ((size_t)((b * NH_ + h) * NC_ + j)) * 4096;
#pragma unroll
    for (int ni = 0; ni < 4; ++ni)
#pragma unroll
        for (int r = 0; r < 4; ++r)
            out[(e0 + quad * 4 + r) * 64 + ni * 16 + lr] = acc[ni][r];
}

// ---------------- exclusive decay scan: one (bh,e,d) lane per thread, coalesced ----------------
__global__ __launch_bounds__(256) void scan_kv_kernel(const float* __restrict__ Cin, bf16* __restrict__ st) {
    const int bh = blockIdx.x >> 4;                       // 16 blocks per bh
    const int f = ((blockIdx.x & 15) << 8) + threadIdx.x; // 0..4095
    const int h = bh & (NH_ - 1);
    const float slope = exp2f(-0.5f * (float)(h + 1));
    const float bdec = __expf(-slope * 128.0f);
    const float* Cb = Cin + (size_t)bh * NC_ * 4096 + f;
    bf16* sb = st + (size_t)bh * NC_ * 4096 + f;
    float carry = 0.f;
#pragma unroll 8
    for (int c = 0; c < NC_; ++c) {
        sb[(size_t)c * 4096] = __float2bfloat16(carry);
        carry = bdec * carry + Cb[(size_t)c * 4096];
    }
}

// ---------------- per-chunk output: O = (mask ∘ qk^T) v + (q*qdec) kv ----------------
__global__ __launch_bounds__(256) void attn_chunk_kernel(const bf16* __restrict__ q, const bf16* __restrict__ k,
                                                         const bf16* __restrict__ v, const bf16* __restrict__ kvst,
                                                         bf16* __restrict__ outb) {
    const int c = blockIdx.x, h = blockIdx.y, b = blockIdx.z;
    const int g = h >> 2;
    const float slope = exp2f(-0.5f * (float)(h + 1));
    __shared__ bf16 qs[128][72];
    __shared__ bf16 ub[128 * 72];   // phase1: k[t][d] stride 72; phase2: vT[e][t] stride 136
    __shared__ bf16 Ps[128][136];
    const int tid = threadIdx.x;
    const int wave = tid >> 6, lane = tid & 63, lr = lane & 15, quad = lane >> 4;
#pragma unroll
    for (int p = 0; p < 4; ++p) {
        int flat = p * 256 + tid;
        int t = flat >> 3, d0 = (flat & 7) * 8;
        size_t row = (size_t)(b * S_ + c * 128 + t);
        *(uint4*)(&qs[t][d0]) = *(const uint4*)(q + row * (NH_ * 64) + h * 64 + d0);
        *(uint4*)(&ub[t * 72 + d0]) = *(const uint4*)(k + row * (NKV_ * 64) + g * 64 + d0);
    }
    __syncthreads();
    const int m0 = wave * 32;
    f32x4 sacc[2][8] = {};
#pragma unroll
    for (int kk = 0; kk < 64; kk += 32) {
        bf16x8 af0 = *(const bf16x8*)(&qs[m0 + lr][kk + quad * 8]);
        bf16x8 af1 = *(const bf16x8*)(&qs[m0 + 16 + lr][kk + quad * 8]);
#pragma unroll
        for (int ni = 0; ni < 8; ++ni) {
            bf16x8 bfr = *(const bf16x8*)(&ub[(ni * 16 + lr) * 72 + kk + quad * 8]);
            sacc[0][ni] = __builtin_amdgcn_mfma_f32_16x16x32_bf16(af0, bfr, sacc[0][ni], 0, 0, 0);
            sacc[1][ni] = __builtin_amdgcn_mfma_f32_16x16x32_bf16(af1, bfr, sacc[1][ni], 0, 0, 0);
        }
    }
    __syncthreads();  // all waves done reading ub (k) before overwrite with vT
#pragma unroll
    for (int mi = 0; mi < 2; ++mi)
#pragma unroll
        for (int ni = 0; ni < 8; ++ni)
#pragma unroll
            for (int r = 0; r < 4; ++r) {
                int t = m0 + mi * 16 + quad * 4 + r;
                int tp = ni * 16 + lr;
                int del = t - tp;
                float val = (del >= 0) ? sacc[mi][ni][r] * __expf(-slope * (float)del) : 0.f;
                Ps[t][tp] = __float2bfloat16(val);
            }
#pragma unroll
    for (int p = 0; p < 4; ++p) {
        int flat = p * 256 + tid;
        int t = flat >> 3, d0 = (flat & 7) * 8;
        size_t row = (size_t)(b * S_ + c * 128 + t);
        uint4 vw = *(const uint4*)(v + row * (NKV_ * 64) + g * 64 + d0);
        const bf16* vp = (const bf16*)&vw;
#pragma unroll
        for (int i = 0; i < 8; ++i) ub[(d0 + i) * 136 + t] = vp[i];
    }
    __syncthreads();
    f32x4 oacc[2][4] = {};
#pragma unroll
    for (int ks2 = 0; ks2 < 128; ks2 += 32) {
        bf16x8 af0 = *(const bf16x8*)(&Ps[m0 + lr][ks2 + quad * 8]);
        bf16x8 af1 = *(const bf16x8*)(&Ps[m0 + 16 + lr][ks2 + quad * 8]);
#pragma unroll
        for (int ni = 0; ni < 4; ++ni) {
            bf16x8 bfv = *(const bf16x8*)(&ub[(ni * 16 + lr) * 136 + ks2 + quad * 8]);
            oacc[0][ni] = __builtin_amdgcn_mfma_f32_16x16x32_bf16(af0, bfv, oacc[0][ni], 0, 0, 0);
            oacc[1][ni] = __builtin_amdgcn_mfma_f32_16x16x32_bf16(af1, bfv, oacc[1][ni], 0, 0, 0);
        }
    }
    const bf16* kvb = kvst + ((size_t)((b * NH_ + h) * NC_ + c)) * 4096;
#pragma unroll
    for (int kk = 0; kk < 64; kk += 32) {
        bf16x8 af[2];
#pragma unroll
        for (int mi = 0; mi < 2; ++mi) {
            bf16x8 a0 = *(const bf16x8*)(&qs[m0 + mi * 16 + lr][kk + quad * 8]);
            float qd = __expf(-slope * (float)(m0 + mi * 16 + lr + 1));
#pragma unroll
            for (int i = 0; i < 8; ++i) a0[i] = (__bf16)((float)a0[i] * qd);
            af[mi] = a0;
        }
#pragma unroll
        for (int ni = 0; ni < 4; ++ni) {
            bf16x8 bk = *(const bf16x8*)(kvb + (ni * 16 + lr) * 64 + kk + quad * 8);
            oacc[0][ni] = __builtin_amdgcn_mfma_f32_16x16x32_bf16(af[0], bk, oacc[0][ni], 0, 0, 0);
            oacc[1][ni] = __builtin_amdgcn_mfma_f32_16x16x32_bf16(af[1], bk, oacc[1][ni], 0, 0, 0);
        }
    }
#pragma unroll
    for (int mi = 0; mi < 2; ++mi)
#pragma unroll
        for (int ni = 0; ni < 4; ++ni)
#pragma unroll
            for (int r = 0; r < 4; ++r) {
                int t = m0 + mi * 16 + quad * 4 + r;
                int e = ni * 16 + lr;
                size_t row = (size_t)(b * S_ + c * 128 + t);
                outb[row * (NH_ * 64) + h * 64 + e] = __float2bfloat16(oacc[mi][ni][r]);
            }
}

extern "C" void kernel_launch(void* const* d_in, const int* in_sizes, int n_in,
                              void* d_out, int out_size, void* d_ws, size_t ws_size,
                              hipStream_t stream) {
    (void)in_sizes; (void)n_in; (void)out_size; (void)ws_size;
    const float* x  = (const float*)d_in[0];
    const float* Wq = (const float*)d_in[1];
    const float* Wk = (const float*)d_in[2];
    const float* Wv = (const float*)d_in[3];
    const float* Wo = (const float*)d_in[4];
    float* out = (float*)d_out;
    char* ws = (char*)d_ws;
    bf16*  xb   = (bf16*)(ws);                    // 33,554,432  (reused as attn_out)
    bf16*  qb   = (bf16*)(ws + 33554432);         // 33,554,432
    bf16*  kb   = (bf16*)(ws + 67108864);         //  8,388,608
    bf16*  vb   = (bf16*)(ws + 75497472);         //  8,388,608
    bf16*  wqb  = (bf16*)(ws + 83886080);         //  2,097,152
    bf16*  wkb  = (bf16*)(ws + 85983232);         //    524,288
    bf16*  wvb  = (bf16*)(ws + 86507520);         //    524,288
    bf16*  wob  = (bf16*)(ws + 87031808);         //  2,097,152
    float* cosd = (float*)(ws + 89128960);        //  1,048,576
    float* sind = (float*)(ws + 90177536);        //  1,048,576
    float* Cbuf = (float*)(ws + 91226112);        // 33,554,432
    bf16*  kvst = (bf16*)(ws + 124780544);        // 16,777,216  -> total 141,557,760 B
    bf16*  attn = xb;

    f2b4_kernel<<<16384, 256, 0, stream>>>(x, xb);
    f2b4_kernel<<<1024, 256, 0, stream>>>(Wq, wqb);
    f2b4_kernel<<<256, 256, 0, stream>>>(Wk, wkb);
    f2b4_kernel<<<256, 256, 0, stream>>>(Wv, wvb);
    f2b4_kernel<<<1024, 256, 0, stream>>>(Wo, wob);
    rope_tab_kernel<<<(S_ * 32) / 256, 256, 0, stream>>>(cosd, sind);

    gemm_bt_kernel<bf16, true><<<dim3(128, 8), 256, 0, stream>>>(xb, wqb, qb, 16384, 1024, 1024, cosd, sind);
    gemm_bt_kernel<bf16, true><<<dim3(128, 2), 256, 0, stream>>>(xb, wkb, kb, 16384, 256, 1024, cosd, sind);
    gemm_bt_kernel<bf16, false><<<dim3(128, 2), 256, 0, stream>>>(xb, wvb, vb, 16384, 256, 1024, cosd, sind);

    chunk_kv_kernel<<<dim3(NC_, NH_, B_), 256, 0, stream>>>(kb, vb, Cbuf);
    scan_kv_kernel<<<512, 256, 0, stream>>>(Cbuf, kvst);
    attn_chunk_kernel<<<dim3(NC_, NH_, B_), 256, 0, stream>>>(qb, kb, vb, kvst, attn);

    gemm_bt_kernel<float, false><<<dim3(128, 8), 256, 0, stream>>>(attn, wob, out, 16384, 1024, 1024, cosd, sind);
}

// Round 3
// 307.930 us; speedup vs baseline: 1.2558x; 1.0926x over previous
//
#include <hip/hip_runtime.h>
#include <hip/hip_bf16.h>

#define B_ 2
#define S_ 8192
#define DIM_ 1024
#define NH_ 16
#define NKV_ 4
#define HD_ 64
#define NC_ 64

typedef __bf16 bf16x8 __attribute__((ext_vector_type(8)));
typedef float f32x4 __attribute__((ext_vector_type(4)));
using bf16 = __hip_bfloat16;

// async global->LDS, 16B per lane; LDS dst = base + lane*16 (wave-uniform base)
#define ASYNC16(gp, lp) __builtin_amdgcn_global_load_lds( \
    (__attribute__((address_space(1))) void*)(void*)(gp), \
    (__attribute__((address_space(3))) void*)(void*)(lp), 16, 0, 0)

// ---------------- fp32 -> bf16 convert (4 elems/thread) ----------------
__global__ __launch_bounds__(256) void f2b4_kernel(const float* __restrict__ in, bf16* __restrict__ out) {
    size_t i = ((size_t)blockIdx.x * 256 + threadIdx.x) * 4;
    const float4 f = *(const float4*)(in + i);
    bf16 t[4];
    t[0] = __float2bfloat16(f.x); t[1] = __float2bfloat16(f.y);
    t[2] = __float2bfloat16(f.z); t[3] = __float2bfloat16(f.w);
    *(uint2*)(out + i) = *(const uint2*)t;
}

// ---------------- fused weight convert: Wq|Wk|Wv -> wqkv (1536x1024), Wo -> wob ----------------
__global__ __launch_bounds__(256) void wconv_kernel(const float* __restrict__ Wq, const float* __restrict__ Wk,
                                                    const float* __restrict__ Wv, const float* __restrict__ Wo,
                                                    bf16* __restrict__ wqkv, bf16* __restrict__ wo) {
    size_t e = ((size_t)blockIdx.x * 256 + threadIdx.x) * 4;  // 2560 blocks -> 2,621,440 elems
    const float* src;
    bf16* dst;
    if (e < 1048576)      { src = Wq + e;           dst = wqkv + e; }
    else if (e < 1310720) { src = Wk + (e - 1048576); dst = wqkv + e; }
    else if (e < 1572864) { src = Wv + (e - 1310720); dst = wqkv + e; }
    else                  { src = Wo + (e - 1572864); dst = wo + (e - 1572864); }
    const float4 f = *(const float4*)src;
    bf16 t[4];
    t[0] = __float2bfloat16(f.x); t[1] = __float2bfloat16(f.y);
    t[2] = __float2bfloat16(f.z); t[3] = __float2bfloat16(f.w);
    *(uint2*)dst = *(const uint2*)t;
}

// ---------------- RoPE tables: f64 range-reduction + hw sin/cos ----------------
__global__ __launch_bounds__(256) void rope_tab_kernel(float* __restrict__ cosd, float* __restrict__ sind) {
    int idx = blockIdx.x * 256 + threadIdx.x;  // S_*32
    int s = idx >> 5, i = idx & 31;
    double inv = exp((double)i * (-9.210340371976184 / 32.0));  // 10000^(-i/32)
    double rev = ((double)s * inv) * 0.15915494309189535;       // angle / 2pi
    double frac = rev - floor(rev);
    float a = (float)frac * 6.2831853071795865f;
    cosd[idx] = __cosf(a);
    sind[idx] = __sinf(a);
}

// ---------------- C[M][N] = A[M][K]*B[N][K]^T, bf16 in, OT out ----------------
// grid (M/128, N/128): x = M-tile so blocks sharing an A-tile have equal id%8 (same XCD).
// Columns < rope_ncols get RoPE applied in the epilogue (wave-uniform: 64-col strips).
template <typename OT>
__global__ __launch_bounds__(256) void gemm_bt_kernel(const bf16* __restrict__ A, const bf16* __restrict__ Bm,
                                                      OT* __restrict__ C, int M, int N, int K, int rope_ncols,
                                                      const float* __restrict__ cosd,
                                                      const float* __restrict__ sind) {
    __shared__ bf16 As[128 * 64];
    __shared__ bf16 Bs[128 * 64];
    const int tid = threadIdx.x;
    const int bm = blockIdx.x * 128, bn = blockIdx.y * 128;
    const int wave = tid >> 6, lane = tid & 63;
    const int wm = (wave >> 1) * 64, wn = (wave & 1) * 64;
    const int lr = lane & 15, quad = lane >> 4;
    // staging: wave stages rows [wave*32, wave*32+32) of both tiles, 4 instrs of 8 rows each
    const int srow = wave * 32;
    const int lrow = lane >> 3;                        // 0..7
    const int lchunk = ((lane & 7) ^ lrow) * 8;        // XOR-swizzled source chunk (elems)
    const bf16* Ag = A + (size_t)(bm + srow + lrow) * K + lchunk;
    const bf16* Bg = Bm + (size_t)(bn + srow + lrow) * K + lchunk;
    f32x4 acc[4][4] = {};
    for (int k0 = 0; k0 < K; k0 += 64) {
#pragma unroll
        for (int p = 0; p < 4; ++p) {
            ASYNC16(Ag + (size_t)(p * 8) * K + k0, &As[(srow + p * 8) * 64]);
            ASYNC16(Bg + (size_t)(p * 8) * K + k0, &Bs[(srow + p * 8) * 64]);
        }
        __syncthreads();
#pragma unroll
        for (int kk = 0; kk < 64; kk += 32) {
            const int sw = (((kk >> 3) + quad) ^ (lr & 7)) << 3;  // de-swizzled chunk offset
            bf16x8 af[4], bfr[4];
#pragma unroll
            for (int i = 0; i < 4; ++i) af[i] = *(const bf16x8*)(&As[(wm + i * 16 + lr) * 64 + sw]);
#pragma unroll
            for (int i = 0; i < 4; ++i) bfr[i] = *(const bf16x8*)(&Bs[(wn + i * 16 + lr) * 64 + sw]);
#pragma unroll
            for (int mi = 0; mi < 4; ++mi)
#pragma unroll
                for (int ni = 0; ni < 4; ++ni)
                    acc[mi][ni] = __builtin_amdgcn_mfma_f32_16x16x32_bf16(af[mi], bfr[ni], acc[mi][ni], 0, 0, 0);
        }
        __syncthreads();
    }
    if (bn + wn < rope_ncols) {
        // wave's 64 columns = exactly one head; pair (i, i+32) = (acc[mi][ni], acc[mi][ni+2])
        // in the same lane, i = ni*16+lr for ni in {0,1}.
#pragma unroll
        for (int mi = 0; mi < 4; ++mi)
#pragma unroll
            for (int r = 0; r < 4; ++r) {
                int row = bm + wm + mi * 16 + quad * 4 + r;
                int s = row & (S_ - 1);
#pragma unroll
                for (int ni = 0; ni < 2; ++ni) {
                    int i = ni * 16 + lr;
                    float cs = cosd[(s << 5) + i];
                    float sn = sind[(s << 5) + i];
                    float x1 = acc[mi][ni][r], x2 = acc[mi][ni + 2][r];
                    acc[mi][ni][r] = x1 * cs - x2 * sn;
                    acc[mi][ni + 2][r] = x2 * cs + x1 * sn;
                }
            }
    }
#pragma unroll
    for (int mi = 0; mi < 4; ++mi)
#pragma unroll
        for (int ni = 0; ni < 4; ++ni)
#pragma unroll
            for (int r = 0; r < 4; ++r) {
                int row = bm + wm + mi * 16 + quad * 4 + r;
                int col = bn + wn + ni * 16 + lr;
                float v = acc[mi][ni][r];
                if constexpr (__is_same(OT, float)) C[(size_t)row * N + col] = v;
                else C[(size_t)row * N + col] = __float2bfloat16(v);
            }
}

// ---------------- per-chunk KV contribution: CT[e][d] = sum_t v[t][e]*k[t][d]*kdec[t] ----------------
// k/v live inside qkv buffer: row stride 1536, k at col 1024+g*64, v at col 1280+g*64
__global__ __launch_bounds__(256) void chunk_kv_kernel(const bf16* __restrict__ qkv, bf16* __restrict__ Cout) {
    const int j = blockIdx.x, h = blockIdx.y, b = blockIdx.z;
    const int g = h >> 2;
    const float slope = exp2f(-0.5f * (float)(h + 1));
    __shared__ bf16 kdT[64][136];
    __shared__ bf16 vT[64][136];
    const int tid = threadIdx.x;
#pragma unroll
    for (int p = 0; p < 4; ++p) {
        int flat = p * 256 + tid;
        int t = flat >> 3, d0 = (flat & 7) * 8;
        const size_t row = (size_t)(b * S_ + j * 128 + t);
        uint4 kw = *(const uint4*)(qkv + row * 1536 + 1024 + g * 64 + d0);
        uint4 vw = *(const uint4*)(qkv + row * 1536 + 1280 + g * 64 + d0);
        float kdec = __expf(-slope * (float)(127 - t));
        const bf16* kp = (const bf16*)&kw;
        const bf16* vp = (const bf16*)&vw;
#pragma unroll
        for (int i = 0; i < 8; ++i) {
            kdT[d0 + i][t] = __float2bfloat16(__bfloat162float(kp[i]) * kdec);
            vT[d0 + i][t] = vp[i];
        }
    }
    __syncthreads();
    const int wave = tid >> 6, lane = tid & 63, lr = lane & 15, quad = lane >> 4;
    const int e0 = wave * 16;
    f32x4 acc[4] = {};
#pragma unroll
    for (int ks = 0; ks < 128; ks += 32) {
        bf16x8 a = *(const bf16x8*)(&vT[e0 + lr][ks + quad * 8]);
#pragma unroll
        for (int ni = 0; ni < 4; ++ni) {
            bf16x8 bb = *(const bf16x8*)(&kdT[ni * 16 + lr][ks + quad * 8]);
            acc[ni] = __builtin_amdgcn_mfma_f32_16x16x32_bf16(a, bb, acc[ni], 0, 0, 0);
        }
    }
    bf16* out = Cout + ((size_t)((b * NH_ + h) * NC_ + j)) * 4096;
#pragma unroll
    for (int ni = 0; ni < 4; ++ni)
#pragma unroll
        for (int r = 0; r < 4; ++r)
            out[(e0 + quad * 4 + r) * 64 + ni * 16 + lr] = __float2bfloat16(acc[ni][r]);
}

// ---------------- exclusive decay scan: one (bh,e,d) lane per thread, coalesced ----------------
__global__ __launch_bounds__(256) void scan_kv_kernel(const bf16* __restrict__ Cin, bf16* __restrict__ st) {
    const int bh = blockIdx.x >> 4;                       // 16 blocks per bh
    const int f = ((blockIdx.x & 15) << 8) + threadIdx.x; // 0..4095
    const int h = bh & (NH_ - 1);
    const float slope = exp2f(-0.5f * (float)(h + 1));
    const float bdec = __expf(-slope * 128.0f);
    const bf16* Cb = Cin + (size_t)bh * NC_ * 4096 + f;
    bf16* sb = st + (size_t)bh * NC_ * 4096 + f;
    float carry = 0.f;
#pragma unroll 8
    for (int c = 0; c < NC_; ++c) {
        sb[(size_t)c * 4096] = __float2bfloat16(carry);
        carry = bdec * carry + __bfloat162float(Cb[(size_t)c * 4096]);
    }
}

// ---------------- per-chunk output: O = (mask ∘ qk^T) v + (q*qdec) kv ----------------
__global__ __launch_bounds__(256) void attn_chunk_kernel(const bf16* __restrict__ qkv, const bf16* __restrict__ kvst,
                                                         bf16* __restrict__ outb) {
    const int c = blockIdx.x, h = blockIdx.y, b = blockIdx.z;
    const int g = h >> 2;
    const float slope = exp2f(-0.5f * (float)(h + 1));
    __shared__ bf16 qs[128][72];
    __shared__ bf16 ub[128 * 72];   // phase1: k[t][d] stride 72; phase2: vT[e][t] stride 136
    __shared__ bf16 Ps[128][136];
    const int tid = threadIdx.x;
    const int wave = tid >> 6, lane = tid & 63, lr = lane & 15, quad = lane >> 4;
#pragma unroll
    for (int p = 0; p < 4; ++p) {
        int flat = p * 256 + tid;
        int t = flat >> 3, d0 = (flat & 7) * 8;
        size_t row = (size_t)(b * S_ + c * 128 + t);
        *(uint4*)(&qs[t][d0]) = *(const uint4*)(qkv + row * 1536 + h * 64 + d0);
        *(uint4*)(&ub[t * 72 + d0]) = *(const uint4*)(qkv + row * 1536 + 1024 + g * 64 + d0);
    }
    __syncthreads();
    const int m0 = wave * 32;
    f32x4 sacc[2][8] = {};
#pragma unroll
    for (int kk = 0; kk < 64; kk += 32) {
        bf16x8 af0 = *(const bf16x8*)(&qs[m0 + lr][kk + quad * 8]);
        bf16x8 af1 = *(const bf16x8*)(&qs[m0 + 16 + lr][kk + quad * 8]);
#pragma unroll
        for (int ni = 0; ni < 8; ++ni) {
            bf16x8 bfr = *(const bf16x8*)(&ub[(ni * 16 + lr) * 72 + kk + quad * 8]);
            sacc[0][ni] = __builtin_amdgcn_mfma_f32_16x16x32_bf16(af0, bfr, sacc[0][ni], 0, 0, 0);
            sacc[1][ni] = __builtin_amdgcn_mfma_f32_16x16x32_bf16(af1, bfr, sacc[1][ni], 0, 0, 0);
        }
    }
    __syncthreads();  // all waves done reading ub (k) before overwrite with vT
#pragma unroll
    for (int mi = 0; mi < 2; ++mi)
#pragma unroll
        for (int ni = 0; ni < 8; ++ni)
#pragma unroll
            for (int r = 0; r < 4; ++r) {
                int t = m0 + mi * 16 + quad * 4 + r;
                int tp = ni * 16 + lr;
                int del = t - tp;
                float val = (del >= 0) ? sacc[mi][ni][r] * __expf(-slope * (float)del) : 0.f;
                Ps[t][tp] = __float2bfloat16(val);
            }
#pragma unroll
    for (int p = 0; p < 4; ++p) {
        int flat = p * 256 + tid;
        int t = flat >> 3, d0 = (flat & 7) * 8;
        size_t row = (size_t)(b * S_ + c * 128 + t);
        uint4 vw = *(const uint4*)(qkv + row * 1536 + 1280 + g * 64 + d0);
        const bf16* vp = (const bf16*)&vw;
#pragma unroll
        for (int i = 0; i < 8; ++i) ub[(d0 + i) * 136 + t] = vp[i];
    }
    __syncthreads();
    f32x4 oacc[2][4] = {};
#pragma unroll
    for (int ks2 = 0; ks2 < 128; ks2 += 32) {
        bf16x8 af0 = *(const bf16x8*)(&Ps[m0 + lr][ks2 + quad * 8]);
        bf16x8 af1 = *(const bf16x8*)(&Ps[m0 + 16 + lr][ks2 + quad * 8]);
#pragma unroll
        for (int ni = 0; ni < 4; ++ni) {
            bf16x8 bfv = *(const bf16x8*)(&ub[(ni * 16 + lr) * 136 + ks2 + quad * 8]);
            oacc[0][ni] = __builtin_amdgcn_mfma_f32_16x16x32_bf16(af0, bfv, oacc[0][ni], 0, 0, 0);
            oacc[1][ni] = __builtin_amdgcn_mfma_f32_16x16x32_bf16(af1, bfv, oacc[1][ni], 0, 0, 0);
        }
    }
    const bf16* kvb = kvst + ((size_t)((b * NH_ + h) * NC_ + c)) * 4096;
#pragma unroll
    for (int kk = 0; kk < 64; kk += 32) {
        bf16x8 af[2];
#pragma unroll
        for (int mi = 0; mi < 2; ++mi) {
            bf16x8 a0 = *(const bf16x8*)(&qs[m0 + mi * 16 + lr][kk + quad * 8]);
            float qd = __expf(-slope * (float)(m0 + mi * 16 + lr + 1));
#pragma unroll
            for (int i = 0; i < 8; ++i) a0[i] = (__bf16)((float)a0[i] * qd);
            af[mi] = a0;
        }
#pragma unroll
        for (int ni = 0; ni < 4; ++ni) {
            bf16x8 bk = *(const bf16x8*)(kvb + (ni * 16 + lr) * 64 + kk + quad * 8);
            oacc[0][ni] = __builtin_amdgcn_mfma_f32_16x16x32_bf16(af[0], bk, oacc[0][ni], 0, 0, 0);
            oacc[1][ni] = __builtin_amdgcn_mfma_f32_16x16x32_bf16(af[1], bk, oacc[1][ni], 0, 0, 0);
        }
    }
#pragma unroll
    for (int mi = 0; mi < 2; ++mi)
#pragma unroll
        for (int ni = 0; ni < 4; ++ni)
#pragma unroll
            for (int r = 0; r < 4; ++r) {
                int t = m0 + mi * 16 + quad * 4 + r;
                int e = ni * 16 + lr;
                size_t row = (size_t)(b * S_ + c * 128 + t);
                outb[row * (NH_ * 64) + h * 64 + e] = __float2bfloat16(oacc[mi][ni][r]);
            }
}

extern "C" void kernel_launch(void* const* d_in, const int* in_sizes, int n_in,
                              void* d_out, int out_size, void* d_ws, size_t ws_size,
                              hipStream_t stream) {
    (void)in_sizes; (void)n_in; (void)out_size; (void)ws_size;
    const float* x  = (const float*)d_in[0];
    const float* Wq = (const float*)d_in[1];
    const float* Wk = (const float*)d_in[2];
    const float* Wv = (const float*)d_in[3];
    const float* Wo = (const float*)d_in[4];
    float* out = (float*)d_out;
    char* ws = (char*)d_ws;
    bf16*  xb    = (bf16*)(ws);                    // 33,554,432 (reused as attn_out)
    bf16*  qkvb  = (bf16*)(ws + 33554432);         // 50,331,648  [M][1536]: q|k|v
    bf16*  wqkvb = (bf16*)(ws + 83886080);         //  3,145,728  [1536][1024]
    bf16*  wob   = (bf16*)(ws + 87031808);         //  2,097,152
    float* cosd  = (float*)(ws + 89128960);        //  1,048,576
    float* sind  = (float*)(ws + 90177536);        //  1,048,576
    bf16*  Cbuf  = (bf16*)(ws + 91226112);         // 16,777,216
    bf16*  kvst  = (bf16*)(ws + 108003328);        // 16,777,216  -> total 124,780,544 B
    bf16*  attn  = xb;

    f2b4_kernel<<<16384, 256, 0, stream>>>(x, xb);
    wconv_kernel<<<2560, 256, 0, stream>>>(Wq, Wk, Wv, Wo, wqkvb, wob);
    rope_tab_kernel<<<(S_ * 32) / 256, 256, 0, stream>>>(cosd, sind);

    // fused q|k|v projection with RoPE on cols < 1280 (q heads + k heads)
    gemm_bt_kernel<bf16><<<dim3(128, 12), 256, 0, stream>>>(xb, wqkvb, qkvb, 16384, 1536, 1024, 1280, cosd, sind);

    chunk_kv_kernel<<<dim3(NC_, NH_, B_), 256, 0, stream>>>(qkvb, Cbuf);
    scan_kv_kernel<<<512, 256, 0, stream>>>(Cbuf, kvst);
    attn_chunk_kernel<<<dim3(NC_, NH_, B_), 256, 0, stream>>>(qkvb, kvst, attn);

    gemm_bt_kernel<float><<<dim3(128, 8), 256, 0, stream>>>(attn, wob, out, 16384, 1024, 1024, 0, cosd, sind);
}

// Round 5
// 267.431 us; speedup vs baseline: 1.4459x; 1.1514x over previous
//
#include <hip/hip_runtime.h>
#include <hip/hip_bf16.h>

#define B_ 2
#define S_ 8192
#define DIM_ 1024
#define NH_ 16
#define NKV_ 4
#define HD_ 64
#define NC_ 64

typedef __bf16 bf16x8 __attribute__((ext_vector_type(8)));
typedef float f32x4 __attribute__((ext_vector_type(4)));
using bf16 = __hip_bfloat16;

// async global->LDS, 16B per lane; LDS dst = base + lane*16 (wave-uniform base)
#define ASYNC16(gp, lp) __builtin_amdgcn_global_load_lds( \
    (__attribute__((address_space(1))) void*)(void*)(gp), \
    (__attribute__((address_space(3))) void*)(void*)(lp), 16, 0, 0)

// ---------------- fused prep: x->bf16, weights->bf16, rope tables ----------------
__global__ __launch_bounds__(256) void prep_kernel(const float* __restrict__ x, const float* __restrict__ Wq,
                                                   const float* __restrict__ Wk, const float* __restrict__ Wv,
                                                   const float* __restrict__ Wo, bf16* __restrict__ xb,
                                                   bf16* __restrict__ wqkv, bf16* __restrict__ wo,
                                                   float* __restrict__ cosd, float* __restrict__ sind) {
    int bid = blockIdx.x;
    if (bid < 16384) {  // x convert: 16,777,216 elems
        size_t i = ((size_t)bid * 256 + threadIdx.x) * 4;
        const float4 f = *(const float4*)(x + i);
        bf16 t[4];
        t[0] = __float2bfloat16(f.x); t[1] = __float2bfloat16(f.y);
        t[2] = __float2bfloat16(f.z); t[3] = __float2bfloat16(f.w);
        *(uint2*)(xb + i) = *(const uint2*)t;
    } else if (bid < 18944) {  // weights: Wq|Wk|Wv -> wqkv, Wo -> wo
        size_t e = ((size_t)(bid - 16384) * 256 + threadIdx.x) * 4;
        const float* src;
        bf16* dst;
        if (e < 1048576)        { src = Wq + e;             dst = wqkv + e; }
        else if (e < 1310720)   { src = Wk + (e - 1048576); dst = wqkv + e; }
        else if (e < 1572864)   { src = Wv + (e - 1310720); dst = wqkv + e; }
        else                    { src = Wo + (e - 1572864); dst = wo + (e - 1572864); }
        const float4 f = *(const float4*)src;
        bf16 t[4];
        t[0] = __float2bfloat16(f.x); t[1] = __float2bfloat16(f.y);
        t[2] = __float2bfloat16(f.z); t[3] = __float2bfloat16(f.w);
        *(uint2*)dst = *(const uint2*)t;
    } else {  // rope tables: S_*32 entries, f64 range-reduction + hw sin/cos
        int idx = (bid - 18944) * 256 + threadIdx.x;
        int s = idx >> 5, i = idx & 31;
        double inv = exp((double)i * (-9.210340371976184 / 32.0));  // 10000^(-i/32)
        double rev = ((double)s * inv) * 0.15915494309189535;       // angle / 2pi
        double frac = rev - floor(rev);
        float a = (float)frac * 6.2831853071795865f;
        cosd[idx] = __cosf(a);
        sind[idx] = __sinf(a);
    }
}

// ---------------- C[M][N] = A[M][K]*B[N][K]^T, bf16 in, OT out ----------------
// grid (M/128, N/128): x = M-tile so blocks sharing an A-tile have equal id%8 (same XCD).
// Columns < rope_ncols get RoPE applied in the epilogue (wave-uniform: 64-col strips).
// launch_bounds(256,3): cap unified regs at ~170 -> 3 blocks/CU co-resident.
template <typename OT>
__global__ __launch_bounds__(256, 3) void gemm_bt_kernel(const bf16* __restrict__ A, const bf16* __restrict__ Bm,
                                                         OT* __restrict__ C, int M, int N, int K, int rope_ncols,
                                                         const float* __restrict__ cosd,
                                                         const float* __restrict__ sind) {
    __shared__ bf16 As[128 * 64];
    __shared__ bf16 Bs[128 * 64];
    const int tid = threadIdx.x;
    const int bm = blockIdx.x * 128, bn = blockIdx.y * 128;
    const int wave = tid >> 6, lane = tid & 63;
    const int wm = (wave >> 1) * 64, wn = (wave & 1) * 64;
    const int lr = lane & 15, quad = lane >> 4;
    const int srow = wave * 32;
    const int lrow = lane >> 3;                        // 0..7
    const int lchunk = ((lane & 7) ^ lrow) * 8;        // XOR-swizzled source chunk (elems)
    const bf16* Ag = A + (size_t)(bm + srow + lrow) * K + lchunk;
    const bf16* Bg = Bm + (size_t)(bn + srow + lrow) * K + lchunk;
    f32x4 acc[4][4] = {};
    for (int k0 = 0; k0 < K; k0 += 64) {
#pragma unroll
        for (int p = 0; p < 4; ++p) {
            ASYNC16(Ag + (size_t)(p * 8) * K + k0, &As[(srow + p * 8) * 64]);
            ASYNC16(Bg + (size_t)(p * 8) * K + k0, &Bs[(srow + p * 8) * 64]);
        }
        __syncthreads();
#pragma unroll
        for (int kk = 0; kk < 64; kk += 32) {
            const int sw = (((kk >> 3) + quad) ^ (lr & 7)) << 3;  // de-swizzled chunk offset
            bf16x8 af[4], bfr[4];
#pragma unroll
            for (int i = 0; i < 4; ++i) af[i] = *(const bf16x8*)(&As[(wm + i * 16 + lr) * 64 + sw]);
#pragma unroll
            for (int i = 0; i < 4; ++i) bfr[i] = *(const bf16x8*)(&Bs[(wn + i * 16 + lr) * 64 + sw]);
#pragma unroll
            for (int mi = 0; mi < 4; ++mi)
#pragma unroll
                for (int ni = 0; ni < 4; ++ni)
                    acc[mi][ni] = __builtin_amdgcn_mfma_f32_16x16x32_bf16(af[mi], bfr[ni], acc[mi][ni], 0, 0, 0);
        }
        __syncthreads();
    }
    if (bn + wn < rope_ncols) {
        // wave's 64 columns = exactly one head; pair (i, i+32) = (acc[mi][ni], acc[mi][ni+2])
#pragma unroll
        for (int mi = 0; mi < 4; ++mi)
#pragma unroll
            for (int r = 0; r < 4; ++r) {
                int row = bm + wm + mi * 16 + quad * 4 + r;
                int s = row & (S_ - 1);
#pragma unroll
                for (int ni = 0; ni < 2; ++ni) {
                    int i = ni * 16 + lr;
                    float cs = cosd[(s << 5) + i];
                    float sn = sind[(s << 5) + i];
                    float x1 = acc[mi][ni][r], x2 = acc[mi][ni + 2][r];
                    acc[mi][ni][r] = x1 * cs - x2 * sn;
                    acc[mi][ni + 2][r] = x2 * cs + x1 * sn;
                }
            }
    }
#pragma unroll
    for (int mi = 0; mi < 4; ++mi)
#pragma unroll
        for (int ni = 0; ni < 4; ++ni)
#pragma unroll
            for (int r = 0; r < 4; ++r) {
                int row = bm + wm + mi * 16 + quad * 4 + r;
                int col = bn + wn + ni * 16 + lr;
                float v = acc[mi][ni][r];
                if constexpr (__is_same(OT, float)) C[(size_t)row * N + col] = v;
                else C[(size_t)row * N + col] = __float2bfloat16(v);
            }
}

// XOR chunk swizzle for transposed LDS tiles (row stride 136 elems, b128-aligned):
// element (row e, col t): addr = e*136 + ((chunk & ~7)<<3) + (((chunk ^ (e>>3)) & 7)<<3) + (t&7),
// chunk = t>>3. Bit 3 of chunk MUST be kept (cols 0..127 -> chunk 0..15); dropping it
// aliases t and t+64 (the R4 NaN bug). Transpose stores hit 8 distinct banks; b128 reads aligned.

// ---------------- per-chunk KV contribution: CT[e][d] = sum_t v[t][e]*k[t][d]*kdec[t] ----------------
__global__ __launch_bounds__(256, 4) void chunk_kv_kernel(const bf16* __restrict__ qkv, bf16* __restrict__ Cout) {
    const int j = blockIdx.x, h = blockIdx.y, b = blockIdx.z;
    const int g = h >> 2;
    const float slope = exp2f(-0.5f * (float)(h + 1));
    __shared__ bf16 kdT[64 * 136];
    __shared__ bf16 vT[64 * 136];
    const int tid = threadIdx.x;
#pragma unroll
    for (int p = 0; p < 4; ++p) {
        int flat = p * 256 + tid;
        int t = flat >> 3, d0 = (flat & 7) * 8;
        const size_t row = (size_t)(b * S_ + j * 128 + t);
        uint4 kw = *(const uint4*)(qkv + row * 1536 + 1024 + g * 64 + d0);
        uint4 vw = *(const uint4*)(qkv + row * 1536 + 1280 + g * 64 + d0);
        float kdec = __expf(-slope * (float)(127 - t));
        const bf16* kp = (const bf16*)&kw;
        const bf16* vp = (const bf16*)&vw;
#pragma unroll
        for (int i = 0; i < 8; ++i) {
            int e = d0 + i;
            int sw = (((t >> 3) & ~7) << 3) + ((((t >> 3) ^ (e >> 3)) & 7) << 3) + (t & 7);
            kdT[e * 136 + sw] = __float2bfloat16(__bfloat162float(kp[i]) * kdec);
            vT[e * 136 + sw] = vp[i];
        }
    }
    __syncthreads();
    const int wave = tid >> 6, lane = tid & 63, lr = lane & 15, quad = lane >> 4;
    const int ew = wave * 16;
    f32x4 acc[4] = {};
#pragma unroll
    for (int ks = 0; ks < 128; ks += 32) {
        int qa = (ks >> 3) + quad;
        int qhi = (qa & ~7) << 3;
        int ea = ew + lr;
        bf16x8 a = *(const bf16x8*)(&vT[ea * 136 + qhi + (((qa ^ (ea >> 3)) & 7) << 3)]);
#pragma unroll
        for (int ni = 0; ni < 4; ++ni) {
            int eb = ni * 16 + lr;
            bf16x8 bb = *(const bf16x8*)(&kdT[eb * 136 + qhi + (((qa ^ (eb >> 3)) & 7) << 3)]);
            acc[ni] = __builtin_amdgcn_mfma_f32_16x16x32_bf16(a, bb, acc[ni], 0, 0, 0);
        }
    }
    bf16* out = Cout + ((size_t)((b * NH_ + h) * NC_ + j)) * 4096;
#pragma unroll
    for (int ni = 0; ni < 4; ++ni)
#pragma unroll
        for (int r = 0; r < 4; ++r)
            out[(ew + quad * 4 + r) * 64 + ni * 16 + lr] = __float2bfloat16(acc[ni][r]);
}

// ---------------- exclusive decay scan: one (bh,e,d) lane per thread, coalesced ----------------
__global__ __launch_bounds__(256) void scan_kv_kernel(const bf16* __restrict__ Cin, bf16* __restrict__ st) {
    const int bh = blockIdx.x >> 4;                       // 16 blocks per bh
    const int f = ((blockIdx.x & 15) << 8) + threadIdx.x; // 0..4095
    const int h = bh & (NH_ - 1);
    const float slope = exp2f(-0.5f * (float)(h + 1));
    const float bdec = __expf(-slope * 128.0f);
    const bf16* Cb = Cin + (size_t)bh * NC_ * 4096 + f;
    bf16* sb = st + (size_t)bh * NC_ * 4096 + f;
    float carry = 0.f;
#pragma unroll 8
    for (int c = 0; c < NC_; ++c) {
        sb[(size_t)c * 4096] = __float2bfloat16(carry);
        carry = bdec * carry + __bfloat162float(Cb[(size_t)c * 4096]);
    }
}

// ---------------- per-chunk output: O = (mask ∘ qk^T) v + (q*qdec) kv ----------------
// LDS overlay: phase1 {qs[128][72], k[128][72]} = 18432 elems; phase2 {Ps[128][136],
// vT[64][136]} = 26112 elems. Union 26112 elems = 52.2 KB -> 3 blocks/CU.
__global__ __launch_bounds__(256, 3) void attn_chunk_kernel(const bf16* __restrict__ qkv,
                                                            const bf16* __restrict__ kvst,
                                                            bf16* __restrict__ outb) {
    const int c = blockIdx.x, h = blockIdx.y, b = blockIdx.z;
    const int g = h >> 2;
    const float slope = exp2f(-0.5f * (float)(h + 1));
    __shared__ bf16 smem[26112];
    bf16* qs  = smem;            // phase1: [128][72]
    bf16* kbs = smem + 9216;     // phase1: [128][72]
    bf16* Ps  = smem;            // phase2: [128][136] swizzled
    bf16* vT  = smem + 17408;    // phase2: [64][136] swizzled
    const int tid = threadIdx.x;
    const int wave = tid >> 6, lane = tid & 63, lr = lane & 15, quad = lane >> 4;
#pragma unroll
    for (int p = 0; p < 4; ++p) {
        int flat = p * 256 + tid;
        int t = flat >> 3, d0 = (flat & 7) * 8;
        size_t row = (size_t)(b * S_ + c * 128 + t);
        *(uint4*)(&qs[t * 72 + d0]) = *(const uint4*)(qkv + row * 1536 + h * 64 + d0);
        *(uint4*)(&kbs[t * 72 + d0]) = *(const uint4*)(qkv + row * 1536 + 1024 + g * 64 + d0);
    }
    __syncthreads();
    const int m0 = wave * 32;
    f32x4 sacc[2][8] = {};
#pragma unroll
    for (int kk = 0; kk < 64; kk += 32) {
        bf16x8 af0 = *(const bf16x8*)(&qs[(m0 + lr) * 72 + kk + quad * 8]);
        bf16x8 af1 = *(const bf16x8*)(&qs[(m0 + 16 + lr) * 72 + kk + quad * 8]);
#pragma unroll
        for (int ni = 0; ni < 8; ++ni) {
            bf16x8 bfr = *(const bf16x8*)(&kbs[(ni * 16 + lr) * 72 + kk + quad * 8]);
            sacc[0][ni] = __builtin_amdgcn_mfma_f32_16x16x32_bf16(af0, bfr, sacc[0][ni], 0, 0, 0);
            sacc[1][ni] = __builtin_amdgcn_mfma_f32_16x16x32_bf16(af1, bfr, sacc[1][ni], 0, 0, 0);
        }
    }
    // qKV term first (qs still live; global kv-state loads overlap)
    f32x4 oacc[2][4] = {};
    const bf16* kvb = kvst + ((size_t)((b * NH_ + h) * NC_ + c)) * 4096;
    float qd0 = __expf(-slope * (float)(m0 + lr + 1));
    float qd1 = __expf(-slope * (float)(m0 + 16 + lr + 1));
#pragma unroll
    for (int kk = 0; kk < 64; kk += 32) {
        bf16x8 a0 = *(const bf16x8*)(&qs[(m0 + lr) * 72 + kk + quad * 8]);
        bf16x8 a1 = *(const bf16x8*)(&qs[(m0 + 16 + lr) * 72 + kk + quad * 8]);
#pragma unroll
        for (int i = 0; i < 8; ++i) {
            a0[i] = (__bf16)((float)a0[i] * qd0);
            a1[i] = (__bf16)((float)a1[i] * qd1);
        }
#pragma unroll
        for (int ni = 0; ni < 4; ++ni) {
            bf16x8 bk = *(const bf16x8*)(kvb + (ni * 16 + lr) * 64 + kk + quad * 8);
            oacc[0][ni] = __builtin_amdgcn_mfma_f32_16x16x32_bf16(a0, bk, oacc[0][ni], 0, 0, 0);
            oacc[1][ni] = __builtin_amdgcn_mfma_f32_16x16x32_bf16(a1, bk, oacc[1][ni], 0, 0, 0);
        }
    }
    __syncthreads();  // qs/kbs fully consumed; region reused for Ps/vT
    // factorized mask: exp(-s*(t-tp)) = exp(-s*(t-m0)) * exp(-s*max(m0-tp,-31))
    float ftv[2][4], gtv[8];
#pragma unroll
    for (int mi = 0; mi < 2; ++mi)
#pragma unroll
        for (int r = 0; r < 4; ++r) ftv[mi][r] = __expf(-slope * (float)(mi * 16 + quad * 4 + r));
#pragma unroll
    for (int ni = 0; ni < 8; ++ni)
        gtv[ni] = __expf(-slope * fmaxf((float)(m0 - (ni * 16 + lr)), -31.0f));
#pragma unroll
    for (int mi = 0; mi < 2; ++mi)
#pragma unroll
        for (int ni = 0; ni < 8; ++ni)
#pragma unroll
            for (int r = 0; r < 4; ++r) {
                int t = m0 + mi * 16 + quad * 4 + r;
                int tp = ni * 16 + lr;
                float val = (t >= tp) ? sacc[mi][ni][r] * ftv[mi][r] * gtv[ni] : 0.f;
                int sw = (((tp >> 3) & ~7) << 3) + ((((tp >> 3) ^ (t >> 3)) & 7) << 3) + (tp & 7);
                Ps[t * 136 + sw] = __float2bfloat16(val);
            }
    // stage v transposed (swizzled)
#pragma unroll
    for (int p = 0; p < 4; ++p) {
        int flat = p * 256 + tid;
        int t = flat >> 3, d0 = (flat & 7) * 8;
        size_t row = (size_t)(b * S_ + c * 128 + t);
        uint4 vw = *(const uint4*)(qkv + row * 1536 + 1280 + g * 64 + d0);
        const bf16* vp = (const bf16*)&vw;
#pragma unroll
        for (int i = 0; i < 8; ++i) {
            int e = d0 + i;
            int sw = (((t >> 3) & ~7) << 3) + ((((t >> 3) ^ (e >> 3)) & 7) << 3) + (t & 7);
            vT[e * 136 + sw] = vp[i];
        }
    }
    __syncthreads();
#pragma unroll
    for (int ks2 = 0; ks2 < 128; ks2 += 32) {
        int qa = (ks2 >> 3) + quad;             // chunk index 0..15
        int qhi = (qa & ~7) << 3;
        int ra0 = m0 + lr, ra1 = m0 + 16 + lr;
        bf16x8 af0 = *(const bf16x8*)(&Ps[ra0 * 136 + qhi + (((qa ^ (ra0 >> 3)) & 7) << 3)]);
        bf16x8 af1 = *(const bf16x8*)(&Ps[ra1 * 136 + qhi + (((qa ^ (ra1 >> 3)) & 7) << 3)]);
#pragma unroll
        for (int ni = 0; ni < 4; ++ni) {
            int eb = ni * 16 + lr;
            bf16x8 bfv = *(const bf16x8*)(&vT[eb * 136 + qhi + (((qa ^ (eb >> 3)) & 7) << 3)]);
            oacc[0][ni] = __builtin_amdgcn_mfma_f32_16x16x32_bf16(af0, bfv, oacc[0][ni], 0, 0, 0);
            oacc[1][ni] = __builtin_amdgcn_mfma_f32_16x16x32_bf16(af1, bfv, oacc[1][ni], 0, 0, 0);
        }
    }
#pragma unroll
    for (int mi = 0; mi < 2; ++mi)
#pragma unroll
        for (int ni = 0; ni < 4; ++ni)
#pragma unroll
            for (int r = 0; r < 4; ++r) {
                int t = m0 + mi * 16 + quad * 4 + r;
                int e = ni * 16 + lr;
                size_t row = (size_t)(b * S_ + c * 128 + t);
                outb[row * (NH_ * 64) + h * 64 + e] = __float2bfloat16(oacc[mi][ni][r]);
            }
}

extern "C" void kernel_launch(void* const* d_in, const int* in_sizes, int n_in,
                              void* d_out, int out_size, void* d_ws, size_t ws_size,
                              hipStream_t stream) {
    (void)in_sizes; (void)n_in; (void)out_size; (void)ws_size;
    const float* x  = (const float*)d_in[0];
    const float* Wq = (const float*)d_in[1];
    const float* Wk = (const float*)d_in[2];
    const float* Wv = (const float*)d_in[3];
    const float* Wo = (const float*)d_in[4];
    float* out = (float*)d_out;
    char* ws = (char*)d_ws;
    bf16*  xb    = (bf16*)(ws);                    // 33,554,432 (reused as attn_out)
    bf16*  qkvb  = (bf16*)(ws + 33554432);         // 50,331,648  [M][1536]: q|k|v
    bf16*  wqkvb = (bf16*)(ws + 83886080);         //  3,145,728  [1536][1024]
    bf16*  wob   = (bf16*)(ws + 87031808);         //  2,097,152
    float* cosd  = (float*)(ws + 89128960);        //  1,048,576
    float* sind  = (float*)(ws + 90177536);        //  1,048,576
    bf16*  Cbuf  = (bf16*)(ws + 91226112);         // 16,777,216
    bf16*  kvst  = (bf16*)(ws + 108003328);        // 16,777,216  -> total 124,780,544 B
    bf16*  attn  = xb;

    prep_kernel<<<19968, 256, 0, stream>>>(x, Wq, Wk, Wv, Wo, xb, wqkvb, wob, cosd, sind);

    // fused q|k|v projection with RoPE on cols < 1280 (q heads + k heads)
    gemm_bt_kernel<bf16><<<dim3(128, 12), 256, 0, stream>>>(xb, wqkvb, qkvb, 16384, 1536, 1024, 1280, cosd, sind);

    chunk_kv_kernel<<<dim3(NC_, NH_, B_), 256, 0, stream>>>(qkvb, Cbuf);
    scan_kv_kernel<<<512, 256, 0, stream>>>(Cbuf, kvst);
    attn_chunk_kernel<<<dim3(NC_, NH_, B_), 256, 0, stream>>>(qkvb, kvst, attn);

    gemm_bt_kernel<float><<<dim3(128, 8), 256, 0, stream>>>(attn, wob, out, 16384, 1024, 1024, 0, cosd, sind);
}